// Round 7
// baseline (580.710 us; speedup 1.0000x reference)
//
#include <hip/hip_runtime.h>

#define NN 100000
#define NE 3200000
#define F 64
#define NR 8
#define PAD 68                 // LDS row stride (floats); all b128 access worst 2-way (free)
#define NCB 98                 // coarse buckets = ceil(NN/1024), bucket = dst>>10
#define CAPC 36864             // capacity per coarse bucket (mean 32768, +22 sigma)
#define CHUNKA 4000            // edges per binA block (800 blocks)
#define NT 1563                // node tiles = ceil(NN/64)
#define SLCAP 2560             // per-tile sorted list capacity (mean 2048, +11 sigma)

// ---------------- init: per-coarse-bucket staging cursors -------------------
__global__ __launch_bounds__(128) void init_kernel(int* __restrict__ cursors) {
    int t = threadIdx.x;
    if (t < NCB) cursors[t] = t * CAPC;
}

// ---------------- pass A: coarse-bin edges (LDS multi-split, burst writes) --
__global__ __launch_bounds__(256) void binA_kernel(
    const int* __restrict__ esrc, const int* __restrict__ edst,
    const int* __restrict__ etyp,
    int* __restrict__ cursors, uint2* __restrict__ stag8)
{
    __shared__ int hist[128];
    __shared__ int start[128];
    __shared__ int cur[NCB];
    __shared__ int gbase[NCB];
    __shared__ uint2 recs[CHUNKA];   // 32 KB

    const int t = threadIdx.x;
    const int e0 = blockIdx.x * CHUNKA;

    if (t < 128) hist[t] = 0;
    __syncthreads();

    uint2 rec[16];
#pragma unroll
    for (int j = 0; j < 16; j++) {
        int i = t + j * 256;
        if (i < CHUNKA) {
            int e = e0 + i;
            unsigned s = (unsigned)esrc[e];
            unsigned d = (unsigned)edst[e];
            unsigned r = (unsigned)etyp[e];
            rec[j] = make_uint2(s, d | (r << 17));
            atomicAdd(&hist[d >> 10], 1);
        }
    }
    __syncthreads();

    if (t < 128) start[t] = hist[t];
    __syncthreads();
    for (int off = 1; off < 128; off <<= 1) {
        int v = 0;
        if (t < 128 && t >= off) v = start[t - off];
        __syncthreads();
        if (t < 128) start[t] += v;
        __syncthreads();
    }
    if (t < 128) start[t] -= hist[t];   // inclusive -> exclusive
    __syncthreads();
    if (t < NCB) {
        cur[t] = start[t];
        gbase[t] = atomicAdd(&cursors[t], hist[t]);   // reserve global run
    }
    __syncthreads();

#pragma unroll
    for (int j = 0; j < 16; j++) {
        int i = t + j * 256;
        if (i < CHUNKA) {
            int b = (int)((rec[j].y & 0x1FFFFu) >> 10);
            int slot = atomicAdd(&cur[b], 1);
            recs[slot] = rec[j];
        }
    }
    __syncthreads();

    // burst write-out: consecutive slots -> consecutive global addrs (~41/run)
#pragma unroll
    for (int j = 0; j < 16; j++) {
        int i = t + j * 256;
        if (i < CHUNKA) {
            uint2 rr = recs[i];
            int b = (int)((rr.y & 0x1FFFFu) >> 10);
            stag8[gbase[b] + (i - start[b])] = rr;
        }
    }
}

// ---------------- pass B: fine-bin, 8 chunk-blocks per coarse bucket --------
// block = (bucket b, chunk c): reorders its slice [c*n/8,(c+1)*n/8) of the
// bucket into 16 tile-runs, written densely into the SAME index range of
// packed4 (deterministic, no global atomics). Descriptor per (chunk,tile).
__global__ __launch_bounds__(256) void binB_kernel(
    const uint2* __restrict__ stag8, const int* __restrict__ cursors,
    unsigned* __restrict__ packed4, unsigned* __restrict__ runsd)
{
    __shared__ int h[16][4];      // 4-copy hist (cuts same-address atomic serialization)
    __shared__ int cu[16][4];
    const int b = blockIdx.x >> 3;
    const int c = blockIdx.x & 7;
    const int t = threadIdx.x;
    const int cp = t & 3;
    const int bbase = b * CAPC;
    const int n = cursors[b] - bbase;
    const int s = (int)(((long long)c * n) >> 3);
    const int e = (int)(((long long)(c + 1) * n) >> 3);
    const int base = bbase + s;      // input AND output base for this chunk
    const int cn = e - s;

    if (t < 64) ((int*)h)[t] = 0;
    __syncthreads();
    for (int i = t; i < cn; i += 256) {
        unsigned y = stag8[base + i].y;
        atomicAdd(&h[(y >> 6) & 15][cp], 1);
    }
    __syncthreads();
    if (t == 0) {
        int acc = 0;
        for (int f = 0; f < 16; f++) {
            int fstart = acc;
#pragma unroll
            for (int k = 0; k < 4; k++) { cu[f][k] = acc; acc += h[f][k]; }
            // descriptor: start[22b] << 10 | cnt[10b]  (cnt mean 256, +43 sigma to 1023)
            runsd[(blockIdx.x << 4) + f] = ((unsigned)(base + fstart) << 10) | (unsigned)(acc - fstart);
        }
    }
    __syncthreads();
    for (int i = t; i < cn; i += 256) {
        uint2 rr = stag8[base + i];
        unsigned f = (rr.y >> 6) & 15u;
        int p = atomicAdd(&cu[f][cp], 1);
        unsigned d = rr.y & 0x1FFFFu;
        unsigned r = rr.y >> 17;
        // packed: src[0:17) | dstLow6[17:23) | rel[23:26)
        packed4[base + p] = rr.x | ((d & 63u) << 17) | (r << 23);
    }
}

// ---------------- fused: LDS counting-sort + wave-per-run gather + GEMM -----
__global__ __launch_bounds__(256) void fused_kernel(
    const float* __restrict__ x,
    const unsigned* __restrict__ packed4,
    const unsigned* __restrict__ runsd,
    const float* __restrict__ weight,   // [8][64][64]
    const float* __restrict__ root,     // [64][64]
    const float* __restrict__ bias,
    float* __restrict__ out)
{
    __shared__ float As[64][PAD];       // row-major: As[node][k]
    __shared__ float Bs[64][PAD];       // Bs[k][fout]
    __shared__ int kstart[512];
    __shared__ int kcur[512];
    __shared__ int slist[SLCAP];
    __shared__ unsigned rdesc[8];

    const int t = threadIdx.x;
    const int tile = blockIdx.x;

    if (t < 8) rdesc[t] = runsd[(((tile >> 4) * 8 + t) << 4) + (tile & 15)];
    kstart[t] = 0; kstart[t + 256] = 0;
    __syncthreads();

    // ---- hist by key9 = rel*64 + dstLow over the 8 runs ----
#pragma unroll
    for (int c = 0; c < 8; c++) {
        unsigned d = rdesc[c];
        int rs = (int)(d >> 10), rc = (int)(d & 1023u);
        for (int i = t; i < rc; i += 256)
            atomicAdd(&kstart[packed4[rs + i] >> 17], 1);
    }
    __syncthreads();
    // ---- exclusive scan of 512 (pairs per thread) ----
    int a0 = kstart[2 * t], a1 = kstart[2 * t + 1];
    int psum = a0 + a1;
    kcur[t] = psum;
    __syncthreads();
    for (int off = 1; off < 256; off <<= 1) {
        int v = (t >= off) ? kcur[t - off] : 0;
        __syncthreads();
        kcur[t] += v;
        __syncthreads();
    }
    int ebase = kcur[t] - psum;
    __syncthreads();
    kstart[2 * t]     = ebase;
    kstart[2 * t + 1] = ebase + a0;
    kcur[2 * t]       = ebase;
    kcur[2 * t + 1]   = ebase + a0;
    __syncthreads();
    // ---- scatter into slist ----
#pragma unroll
    for (int c = 0; c < 8; c++) {
        unsigned d = rdesc[c];
        int rs = (int)(d >> 10), rc = (int)(d & 1023u);
        for (int i = t; i < rc; i += 256) {
            unsigned p = packed4[rs + i];
            int slot = atomicAdd(&kcur[p >> 17], 1);
            slist[slot] = (int)(p & 0x1FFFFu);
        }
    }
    __syncthreads();   // kcur[k] == end of run k

    // ---- per-wave gather + GEMM ----
    const int lane = t & 63;
    const int w = t >> 6;               // wave 0..3: owns nodes [16w, 16w+16)
    const int node0 = tile * 64;
    const int tx = t & 15;              // fout group
    const int ty = t >> 4;              // node group 0..15

    float4 acc[4];
#pragma unroll
    for (int i = 0; i < 4; i++) acc[i] = make_float4(0.f, 0.f, 0.f, 0.f);

    for (int seg = 0; seg < 9; seg++) {
        const float* __restrict__ Wseg = (seg == 0) ? root : (weight + (size_t)(seg - 1) * (F * F));
        __syncthreads();
        // stage B: 4 float4 per thread, coalesced global read
#pragma unroll
        for (int j = 0; j < 4; j++) {
            int g = j * 1024 + t * 4;
            float4 v = *(const float4*)(Wseg + g);
            *(float4*)&Bs[g >> 6][g & 63] = v;
        }
        // stage A: lane = feature, wave iterates its 16 nodes; row writes (conflict-free)
        if (seg == 0) {
            for (int nn = w * 16; nn < w * 16 + 16; nn++) {
                int node = min(node0 + nn, NN - 1);
                As[nn][lane] = x[(size_t)node * F + lane];
            }
        } else {
            for (int nn = w * 16; nn < w * 16 + 16; nn++) {
                int key = ((seg - 1) << 6) | nn;
                int beg = kstart[key], end = kcur[key];
                float a = 0.f;
                int i = beg;
                for (; i + 4 <= end; i += 4) {
                    int s0 = slist[i], s1 = slist[i + 1], s2 = slist[i + 2], s3 = slist[i + 3];
                    float v0 = x[(size_t)s0 * F + lane];
                    float v1 = x[(size_t)s1 * F + lane];
                    float v2 = x[(size_t)s2 * F + lane];
                    float v3 = x[(size_t)s3 * F + lane];
                    a += (v0 + v1) + (v2 + v3);
                }
                for (; i < end; i++) a += x[(size_t)slist[i] * F + lane];
                float scl = 1.0f / (float)max(end - beg, 1);
                As[nn][lane] = a * scl;
            }
        }
        __syncthreads();

        // GEMM: 4x4 register tile, k-blocked by 4, all-b128 LDS reads
#pragma unroll 4
        for (int k4 = 0; k4 < 64; k4 += 4) {
            float4 b0 = *(const float4*)&Bs[k4 + 0][tx << 2];
            float4 b1 = *(const float4*)&Bs[k4 + 1][tx << 2];
            float4 b2 = *(const float4*)&Bs[k4 + 2][tx << 2];
            float4 b3 = *(const float4*)&Bs[k4 + 3][tx << 2];
#pragma unroll
            for (int i = 0; i < 4; i++) {
                float4 a = *(const float4*)&As[(ty << 2) + i][k4];
                acc[i].x = fmaf(a.x, b0.x, acc[i].x);
                acc[i].y = fmaf(a.x, b0.y, acc[i].y);
                acc[i].z = fmaf(a.x, b0.z, acc[i].z);
                acc[i].w = fmaf(a.x, b0.w, acc[i].w);
                acc[i].x = fmaf(a.y, b1.x, acc[i].x);
                acc[i].y = fmaf(a.y, b1.y, acc[i].y);
                acc[i].z = fmaf(a.y, b1.z, acc[i].z);
                acc[i].w = fmaf(a.y, b1.w, acc[i].w);
                acc[i].x = fmaf(a.z, b2.x, acc[i].x);
                acc[i].y = fmaf(a.z, b2.y, acc[i].y);
                acc[i].z = fmaf(a.z, b2.z, acc[i].z);
                acc[i].w = fmaf(a.z, b2.w, acc[i].w);
                acc[i].x = fmaf(a.w, b3.x, acc[i].x);
                acc[i].y = fmaf(a.w, b3.y, acc[i].y);
                acc[i].z = fmaf(a.w, b3.z, acc[i].z);
                acc[i].w = fmaf(a.w, b3.w, acc[i].w);
            }
        }
    }

    // epilogue: + bias, coalesced float4 stores
    float4 bv = *(const float4*)(bias + (tx << 2));
#pragma unroll
    for (int i = 0; i < 4; i++) {
        int node = node0 + (ty << 2) + i;
        if (node < NN) {
            float4 o = make_float4(acc[i].x + bv.x, acc[i].y + bv.y,
                                   acc[i].z + bv.z, acc[i].w + bv.w);
            *(float4*)(out + (size_t)node * F + (tx << 2)) = o;
        }
    }
}

extern "C" void kernel_launch(void* const* d_in, const int* in_sizes, int n_in,
                              void* d_out, int out_size, void* d_ws, size_t ws_size,
                              hipStream_t stream) {
    const float* x    = (const float*)d_in[0];
    const int*   ei   = (const int*)d_in[1];   // [2, NE]: row0 = src, row1 = dst
    const int*   et   = (const int*)d_in[2];
    const float* wgt  = (const float*)d_in[3];
    const float* root = (const float*)d_in[4];
    const float* bias = (const float*)d_in[5];
    float*       out  = (float*)d_out;

    // workspace layout
    int*      cursors = (int*)d_ws;                                   // [128]      512 B
    unsigned* runsd   = (unsigned*)((char*)d_ws + 512);               // [784*16]   50 KB
    uint2*    stag8   = (uint2*)((char*)d_ws + 512 + 50176);          // [NCB*CAPC] 28.9 MB
    unsigned* packed4 = (unsigned*)(stag8 + (size_t)NCB * CAPC);      // [NCB*CAPC] 14.5 MB

    init_kernel<<<1, 128, 0, stream>>>(cursors);
    binA_kernel<<<NE / CHUNKA, 256, 0, stream>>>(ei, ei + NE, et, cursors, stag8);
    binB_kernel<<<NCB * 8, 256, 0, stream>>>(stag8, cursors, packed4, runsd);
    fused_kernel<<<NT, 256, 0, stream>>>(x, packed4, runsd, wgt, root, bias, out);
}